// Round 3
// baseline (492.137 us; speedup 1.0000x reference)
//
#include <hip/hip_runtime.h>

// y[r, 4g+j] = sum_k blocks[g][j][k] * x[r, 4g+k]   (g < 1024)
// y[r, 4096+i] = diag[i] * x[r, 4096+i]             (i < 3)
// 16384 rows of 4099 f32. Row stride 16396 B == 12 (mod 16): only every
// 4th row is float4-aligned. Tile = 4 consecutive rows per WG -> the tile
// is a contiguous, 16B-aligned 65584 B span of x (and of y).
constexpr int NROW = 16384;
constexpr int ROWF = 4099;
constexpr int TR   = 4;
constexpr int NWG  = NROW / TR;        // 4096 workgroups
constexpr int WIN  = 3 * ROWF + 3;     // 12300 floats: rows 1..3 + row0's 3-float rem head
// WIN = 3075 float4s = 49200 B of LDS  -> 3 WGs/CU

__global__ __launch_bounds__(256) void blockcore_fused(
    const float* __restrict__ x,
    const float* __restrict__ blocks,
    const float* __restrict__ diag,
    float* __restrict__ y)
{
    __shared__ float lds[WIN];
    const int t  = threadIdx.x;
    const int wg = blockIdx.x;
    const size_t r0       = (size_t)wg * TR;
    const size_t start_al = r0 * ROWF + 4096;   // float idx; byte offset % 16 == 0

    const float4* xw = reinterpret_cast<const float4*>(x + start_al);
    float4*       lw = reinterpret_cast<float4*>(lds);

    // ---- issue staging loads for rows 1..3 window (3075 vec4s, coalesced) ----
    float4 sr[13];
    #pragma unroll
    for (int i = 0; i < 12; ++i) sr[i] = xw[t + 256 * i];
    if (t < 3) sr[12] = xw[3072 + t];

    // ---- row 0 (aligned) direct path, quad-cooperative, overlaps staging ----
    const int q = t >> 2, j = t & 3;
    const float* xr0 = x + r0 * ROWF;
    float*       yr0 = y + r0 * ROWF;
    #pragma unroll 4
    for (int i = 0; i < 16; ++i) {
        const int g = q + 64 * i;
        const float4 xv = *reinterpret_cast<const float4*>(xr0 + 4 * g);     // quad-broadcast
        const float4 bv = *reinterpret_cast<const float4*>(blocks + 16 * g + 4 * j); // 1KB/wave, L1
        yr0[4 * g + j] = bv.x * xv.x + bv.y * xv.y + bv.z * xv.z + bv.w * xv.w;
    }

    // ---- commit staged x to LDS (linear, 1KB/wave contiguous) ----
    #pragma unroll
    for (int i = 0; i < 12; ++i) lw[t + 256 * i] = sr[i];
    if (t < 3) lw[3072 + t] = sr[12];
    __syncthreads();

    // ---- in-place compute in LDS ----
    // head: row0's diagonal remainder (window floats 0..2)
    if (t < 3) lds[t] *= diag[t];
    // rows 1..3: quad (q) owns group gg, lane j computes output j; blocks row
    // register-held across the 3 rows. Reads are quad-broadcast (2-way banks,
    // free); writes are 256B-contiguous per wave.
    for (int it = 0; it < 17; ++it) {
        const int gg = q + 64 * it;
        if (gg < 1024) {
            const float4 bv = *reinterpret_cast<const float4*>(blocks + 16 * gg + 4 * j);
            #pragma unroll
            for (int lr = 0; lr < 3; ++lr) {
                const int base = lr * ROWF + 4 * gg + 3;
                const float x0 = lds[base + 0], x1 = lds[base + 1];
                const float x2 = lds[base + 2], x3 = lds[base + 3];
                // wave-lockstep: all quad lanes read before any lane writes
                lds[base + j] = bv.x * x0 + bv.y * x1 + bv.z * x2 + bv.w * x3;
            }
        } else if (gg == 1024 && j < 3) {
            #pragma unroll
            for (int lr = 0; lr < 3; ++lr)
                lds[(lr + 1) * ROWF + j] *= diag[j];   // rem of rows 1..3
        }
    }
    __syncthreads();

    // ---- store window back (coalesced vec4) ----
    float4* yw = reinterpret_cast<float4*>(y + start_al);
    #pragma unroll
    for (int i = 0; i < 12; ++i) yw[t + 256 * i] = lw[t + 256 * i];
    if (t < 3) yw[3072 + t] = lw[3072 + t];
}

extern "C" void kernel_launch(void* const* d_in, const int* in_sizes, int n_in,
                              void* d_out, int out_size, void* d_ws, size_t ws_size,
                              hipStream_t stream) {
    const float* x      = (const float*)d_in[0];
    const float* blocks = (const float*)d_in[1];
    const float* diag   = (const float*)d_in[2];
    float*       y      = (float*)d_out;

    blockcore_fused<<<dim3(NWG), dim3(256), 0, stream>>>(x, blocks, diag, y);
}